// Round 3
// baseline (83.826 us; speedup 1.0000x reference)
//
#include <hip/hip_runtime.h>
#include <math.h>

// ---------------------------------------------------------------------------
// Fully fused QNN: one block per batch row. Threads 0..195 each simulate one
// 4-qubit circuit with the 16 complex amplitudes held in 32 *named scalar
// registers* (macro-generated gates -> no array -> no scratch spill).
// Features -> LDS -> fc1 (4 waves x 16 outputs, coalesced w1, shuffle
// reduce) -> fc2 (10 threads) -> out.  Qubit q == bit (3-q) of amp index.
// ---------------------------------------------------------------------------

#define PI_F 3.14159265358979323846f

// Ry: a' = c*a - s*b ; b' = s*a + c*b
#define RY_PAIR(a,b) { float ax=sr##a, ay=si##a, bx=sr##b, by=si##b; \
  sr##a = c_*ax - sn_*bx;  si##a = c_*ay - sn_*by; \
  sr##b = sn_*ax + c_*bx;  si##b = sn_*ay + c_*by; }

// Rx: a' = c*a - i s*b ; b' = -i s*a + c*b
#define RX_PAIR(a,b) { float ax=sr##a, ay=si##a, bx=sr##b, by=si##b; \
  sr##a = c_*ax + sn_*by;  si##a = c_*ay - sn_*bx; \
  sr##b = sn_*ay + c_*bx;  si##b = c_*by - sn_*ax; }

// Rz lo (bit clear): *= e^{-it/2};  hi (bit set): *= e^{+it/2}
#define RZ_LO(a) { float ax=sr##a, ay=si##a; sr##a = ax*c_ + ay*sn_; si##a = ay*c_ - ax*sn_; }
#define RZ_HI(a) { float ax=sr##a, ay=si##a; sr##a = ax*c_ - ay*sn_; si##a = ay*c_ + ax*sn_; }

#define SWAP_AMP(a,b) { float tx=sr##a, ty=si##a; sr##a=sr##b; si##a=si##b; sr##b=tx; si##b=ty; }

#define RY_M8 RY_PAIR(0,8)  RY_PAIR(1,9)  RY_PAIR(2,10) RY_PAIR(3,11) RY_PAIR(4,12) RY_PAIR(5,13) RY_PAIR(6,14) RY_PAIR(7,15)
#define RY_M4 RY_PAIR(0,4)  RY_PAIR(1,5)  RY_PAIR(2,6)  RY_PAIR(3,7)  RY_PAIR(8,12) RY_PAIR(9,13) RY_PAIR(10,14) RY_PAIR(11,15)
#define RY_M2 RY_PAIR(0,2)  RY_PAIR(1,3)  RY_PAIR(4,6)  RY_PAIR(5,7)  RY_PAIR(8,10) RY_PAIR(9,11) RY_PAIR(12,14) RY_PAIR(13,15)
#define RY_M1 RY_PAIR(0,1)  RY_PAIR(2,3)  RY_PAIR(4,5)  RY_PAIR(6,7)  RY_PAIR(8,9)  RY_PAIR(10,11) RY_PAIR(12,13) RY_PAIR(14,15)

#define RX_M8 RX_PAIR(0,8)  RX_PAIR(1,9)  RX_PAIR(2,10) RX_PAIR(3,11) RX_PAIR(4,12) RX_PAIR(5,13) RX_PAIR(6,14) RX_PAIR(7,15)
#define RX_M4 RX_PAIR(0,4)  RX_PAIR(1,5)  RX_PAIR(2,6)  RX_PAIR(3,7)  RX_PAIR(8,12) RX_PAIR(9,13) RX_PAIR(10,14) RX_PAIR(11,15)
#define RX_M2 RX_PAIR(0,2)  RX_PAIR(1,3)  RX_PAIR(4,6)  RX_PAIR(5,7)  RX_PAIR(8,10) RX_PAIR(9,11) RX_PAIR(12,14) RX_PAIR(13,15)
#define RX_M1 RX_PAIR(0,1)  RX_PAIR(2,3)  RX_PAIR(4,5)  RX_PAIR(6,7)  RX_PAIR(8,9)  RX_PAIR(10,11) RX_PAIR(12,13) RX_PAIR(14,15)

#define RZ_M8 RZ_LO(0) RZ_LO(1) RZ_LO(2)  RZ_LO(3)  RZ_LO(4)  RZ_LO(5)  RZ_LO(6)  RZ_LO(7) \
              RZ_HI(8) RZ_HI(9) RZ_HI(10) RZ_HI(11) RZ_HI(12) RZ_HI(13) RZ_HI(14) RZ_HI(15)
#define RZ_M4 RZ_LO(0) RZ_LO(1) RZ_LO(2)  RZ_LO(3)  RZ_HI(4)  RZ_HI(5)  RZ_HI(6)  RZ_HI(7) \
              RZ_LO(8) RZ_LO(9) RZ_LO(10) RZ_LO(11) RZ_HI(12) RZ_HI(13) RZ_HI(14) RZ_HI(15)
#define RZ_M2 RZ_LO(0) RZ_LO(1) RZ_HI(2)  RZ_HI(3)  RZ_LO(4)  RZ_LO(5)  RZ_HI(6)  RZ_HI(7) \
              RZ_LO(8) RZ_LO(9) RZ_HI(10) RZ_HI(11) RZ_LO(12) RZ_LO(13) RZ_HI(14) RZ_HI(15)
#define RZ_M1 RZ_LO(0) RZ_HI(1) RZ_LO(2)  RZ_HI(3)  RZ_LO(4)  RZ_HI(5)  RZ_LO(6)  RZ_HI(7) \
              RZ_LO(8) RZ_HI(9) RZ_LO(10) RZ_HI(11) RZ_LO(12) RZ_HI(13) RZ_LO(14) RZ_HI(15)

// CNOT(ctrl=bit c, tgt=bit t): swap |c=1,t=0> <-> |c=1,t=1>
#define CNOT_0_1 SWAP_AMP(8,12)  SWAP_AMP(9,13)  SWAP_AMP(10,14) SWAP_AMP(11,15)
#define CNOT_1_2 SWAP_AMP(4,6)   SWAP_AMP(5,7)   SWAP_AMP(12,14) SWAP_AMP(13,15)
#define CNOT_2_3 SWAP_AMP(2,3)   SWAP_AMP(6,7)   SWAP_AMP(10,11) SWAP_AMP(14,15)
#define CNOT_3_0 SWAP_AMP(1,9)   SWAP_AMP(3,11)  SWAP_AMP(5,13)  SWAP_AMP(7,15)

__global__ __launch_bounds__(256) void fused_qnet_kernel(
    const float* __restrict__ x,      // [128,1,28,28]
    const float* __restrict__ w,      // [60]
    const float* __restrict__ w1,     // [64,784]
    const float* __restrict__ b1,     // [64]
    const float* __restrict__ w2,     // [10,64]
    const float* __restrict__ b2,     // [10]
    float* __restrict__ out) {        // [128,10]
  __shared__ float wc[60], wsn[60];
  __shared__ float f[784];
  __shared__ float h[64];

  const int t = threadIdx.x;
  const int b = blockIdx.x;

  if (t < 60) {
    float s_, c_;
    __sincosf(w[t] * 0.5f, &s_, &c_);
    wsn[t] = s_; wc[t] = c_;
  }
  __syncthreads();

  // ---------------- phase 1: quantum circuits ------------------------------
  if (t < 196) {
    const int pi_ = t / 14, pj = t - pi_ * 14;
    const float* xb = x + b * 784 + (2 * pi_) * 28 + 2 * pj;
    const float a0 = xb[0], a1 = xb[1], a2 = xb[28], a3 = xb[29];

    float sr0 = 1.f, si0 = 0.f;
    float sr1 = 0.f, si1 = 0.f, sr2 = 0.f, si2 = 0.f, sr3 = 0.f, si3 = 0.f;
    float sr4 = 0.f, si4 = 0.f, sr5 = 0.f, si5 = 0.f, sr6 = 0.f, si6 = 0.f;
    float sr7 = 0.f, si7 = 0.f, sr8 = 0.f, si8 = 0.f, sr9 = 0.f, si9 = 0.f;
    float sr10 = 0.f, si10 = 0.f, sr11 = 0.f, si11 = 0.f, sr12 = 0.f, si12 = 0.f;
    float sr13 = 0.f, si13 = 0.f, sr14 = 0.f, si14 = 0.f, sr15 = 0.f, si15 = 0.f;

    float c_, sn_;
    __sincosf(PI_F * a0, &sn_, &c_); { RX_M8 }
    __sincosf(PI_F * a1, &sn_, &c_); { RX_M4 }
    __sincosf(PI_F * a2, &sn_, &c_); { RX_M2 }
    __sincosf(PI_F * a3, &sn_, &c_); { RX_M1 }

#pragma unroll
    for (int l = 0; l < 5; ++l) {
      const int o = 12 * l;
      c_ = wc[o + 0];  sn_ = wsn[o + 0];  { RY_M8 }
      c_ = wc[o + 1];  sn_ = wsn[o + 1];  { RY_M4 }
      c_ = wc[o + 2];  sn_ = wsn[o + 2];  { RY_M2 }
      c_ = wc[o + 3];  sn_ = wsn[o + 3];  { RY_M1 }
      c_ = wc[o + 4];  sn_ = wsn[o + 4];  { RZ_M8 }
      c_ = wc[o + 5];  sn_ = wsn[o + 5];  { RZ_M4 }
      c_ = wc[o + 6];  sn_ = wsn[o + 6];  { RZ_M2 }
      c_ = wc[o + 7];  sn_ = wsn[o + 7];  { RZ_M1 }
      c_ = wc[o + 8];  sn_ = wsn[o + 8];  { RY_M8 }
      c_ = wc[o + 9];  sn_ = wsn[o + 9];  { RY_M4 }
      c_ = wc[o + 10]; sn_ = wsn[o + 10]; { RY_M2 }
      c_ = wc[o + 11]; sn_ = wsn[o + 11]; { RY_M1 }
      if (l < 4) { CNOT_0_1  CNOT_1_2  CNOT_2_3  CNOT_3_0 }
    }

    float pr[16];
#define PROB(i) pr[i] = sr##i * sr##i + si##i * si##i;
    PROB(0) PROB(1) PROB(2) PROB(3) PROB(4) PROB(5) PROB(6) PROB(7)
    PROB(8) PROB(9) PROB(10) PROB(11) PROB(12) PROB(13) PROB(14) PROB(15)
#undef PROB
    float e0 = 0.f, e1 = 0.f, e2 = 0.f, e3 = 0.f;
#pragma unroll
    for (int i = 0; i < 16; ++i) {
      e0 += (i & 8) ? -pr[i] : pr[i];
      e1 += (i & 4) ? -pr[i] : pr[i];
      e2 += (i & 2) ? -pr[i] : pr[i];
      e3 += (i & 1) ? -pr[i] : pr[i];
    }
    float4* fv = (float4*)(f + t * 4);
    *fv = make_float4(e0, e1, e2, e3);
  }
  __syncthreads();

  // ---------------- phase 2: fc1 (64 outputs, 4 waves x 16) ----------------
  const int wv = t >> 6;
  const int l  = t & 63;

  float fr[12];
#pragma unroll
  for (int it = 0; it < 12; ++it) fr[it] = f[it * 64 + l];
  const float ft = (l < 16) ? f[768 + l] : 0.f;

#pragma unroll
  for (int jj = 0; jj < 16; ++jj) {
    const int j = wv * 16 + jj;
    const float* wr = w1 + j * 784;
    float acc = (l < 16) ? ft * wr[768 + l] : 0.f;
#pragma unroll
    for (int it = 0; it < 12; ++it)
      acc = fmaf(fr[it], wr[it * 64 + l], acc);
#pragma unroll
    for (int off = 32; off > 0; off >>= 1)
      acc += __shfl_down(acc, off, 64);
    if (l == 0) h[j] = fmaxf(acc + b1[j], 0.f);
  }
  __syncthreads();

  // ---------------- phase 3: fc2 (10 outputs) ------------------------------
  if (t < 10) {
    float o = b2[t];
    const float* w2r = w2 + t * 64;
#pragma unroll
    for (int k = 0; k < 64; ++k) o = fmaf(h[k], w2r[k], o);
    out[b * 10 + t] = o;
  }
}

extern "C" void kernel_launch(void* const* d_in, const int* in_sizes, int n_in,
                              void* d_out, int out_size, void* d_ws, size_t ws_size,
                              hipStream_t stream) {
  const float* x    = (const float*)d_in[0];   // [128,1,28,28]
  const float* w    = (const float*)d_in[1];   // [60]
  const float* w1   = (const float*)d_in[2];   // [64,784]
  const float* b1   = (const float*)d_in[3];   // [64]
  const float* w2   = (const float*)d_in[4];   // [10,64]
  const float* b2   = (const float*)d_in[5];   // [10]
  float* out = (float*)d_out;                  // [128,10]

  fused_qnet_kernel<<<128, 256, 0, stream>>>(x, w, w1, b1, w2, b2, out);
}